// Round 10
// baseline (325.688 us; speedup 1.0000x reference)
//
#include <hip/hip_runtime.h>

#define N_NODES 20000
#define N_PAD 20032
#define F_IN 64
#define HID 128
#define HEADS 4
#define E_EDGES 320000
#define ET (E_EDGES + N_NODES)   // + self loops
#define NEG_SLOPE 0.2f
#define LNODES 16                // nodes per gat_layer block

typedef unsigned short ushort_t;
typedef unsigned int uint_t;

using bf16x8 = __attribute__((ext_vector_type(8))) short;
using f32x4  = __attribute__((ext_vector_type(4))) float;

__device__ __forceinline__ ushort_t f2bf(float f) {
    union { float f; uint_t u; } v; v.f = f;
    uint_t r = v.u + 0x7fffu + ((v.u >> 16) & 1u);   // round-to-nearest-even
    return (ushort_t)(r >> 16);
}
__device__ __forceinline__ float bflo(uint_t w) {
    union { uint_t u; float f; } v; v.u = w << 16; return v.f;
}
__device__ __forceinline__ float bfhi(uint_t w) {
    union { uint_t u; float f; } v; v.u = w & 0xffff0000u; return v.f;
}

// ---------------------------------------------------------------------------
// ONE pack kernel: Bp (W-bar bf16), wtS/wtD (f32), W1p (bf16), deg clear.
__global__ __launch_bounds__(256) void pack_all(const float* __restrict__ lin,
                                                const float* __restrict__ attS,
                                                const float* __restrict__ attD,
                                                const float* __restrict__ W1,
                                                ushort_t* __restrict__ Bp,
                                                float* __restrict__ wtS,
                                                float* __restrict__ wtD,
                                                ushort_t* __restrict__ W1p,
                                                int* __restrict__ deg) {
    int idx = blockIdx.x * 256 + threadIdx.x;
    if (idx < N_NODES) deg[idx] = 0;

    {   // job A: Bp[l][col][kk] = lin[l][kk&127][(kk>>7)*128 + col]
        int l = idx / 8192;
        int rem = idx % 8192;
        int col = rem / 64, kg = rem % 64;
        const float* W = lin + (size_t)l * 128 * 512;
        int h = kg >> 4;
        int kbase = (kg & 15) * 8;
        ushort_t tmp[8];
#pragma unroll
        for (int j = 0; j < 8; ++j)
            tmp[j] = f2bf(W[(size_t)(kbase + j) * 512 + h * 128 + col]);
        *(uint4*)(Bp + ((size_t)(l * 128 + col)) * 512 + kg * 8) = *(const uint4*)tmp;
    }

    if (idx < 1536) {   // job B: w-tilde
        int l = idx / 512;
        int rem = idx % 512;
        int h = rem >> 7, k = rem & 127;
        const float* W = lin + (size_t)l * 128 * 512 + (size_t)k * 512 + h * 128;
        const float* as = attS + (size_t)l * 512 + h * 128;
        const float* ad = attD + (size_t)l * 512 + h * 128;
        float ss = 0.f, sd = 0.f;
        for (int d = 0; d < 128; ++d) {
            float w = W[d];
            ss = fmaf(w, as[d], ss);
            sd = fmaf(w, ad[d], sd);
        }
        wtS[idx] = ss;
        wtD[idx] = sd;
    }

    if (idx < 1024) {   // job C: W1p
        int col = idx >> 4, kg = idx & 15;
        ushort_t tmp[8];
#pragma unroll
        for (int j = 0; j < 8; ++j)
            tmp[j] = f2bf(W1[(size_t)(kg * 8 + j) * 64 + col]);
        *(uint4*)(W1p + (size_t)col * 128 + kg * 8) = *(const uint4*)tmp;
    }
}

// ---------------------------------------------------------------------------
// Fused encoder + degree histogram.
#define ENC_BLOCKS 1250
__global__ __launch_bounds__(256) void enc_hist(const float* __restrict__ nf,
                                                const float* __restrict__ W,
                                                const float* __restrict__ b,
                                                const int* __restrict__ ei,
                                                float* __restrict__ x,
                                                ushort_t* __restrict__ xb,
                                                int* __restrict__ deg) {
    int t = threadIdx.x;
    if (blockIdx.x < ENC_BLOCKS) {
        __shared__ float xs[16][64];
        int n0 = blockIdx.x * 16;
        ((float4*)&xs[0][0])[t] = ((const float4*)(nf + (size_t)n0 * 64))[t];
        __syncthreads();
        int c = t & 127, ng = t >> 7;
        float acc[8];
#pragma unroll
        for (int i = 0; i < 8; ++i) acc[i] = 0.f;
        for (int k = 0; k < 64; ++k) {
            float wv = W[k * 128 + c];
#pragma unroll
            for (int i = 0; i < 8; ++i) acc[i] = fmaf(xs[ng * 8 + i][k], wv, acc[i]);
        }
        float bias = b[c];
#pragma unroll
        for (int i = 0; i < 8; ++i) {
            float v = acc[i] + bias;
            v = v > 0.f ? v : 0.f;
            int row = n0 + ng * 8 + i;
            x[(size_t)row * 128 + c] = v;
            xb[(size_t)row * 128 + c] = f2bf(v);
        }
    } else {
        int e = (blockIdx.x - ENC_BLOCKS) * 256 + t;
        if (e < ET) {
            int d = (e < E_EDGES) ? ei[E_EDGES + e] : (e - E_EDGES);
            atomicAdd(&deg[d], 1);
        }
    }
}

// ---------------------------------------------------------------------------
__global__ __launch_bounds__(1024) void scan_kernel(const int* __restrict__ deg,
                                                    int* __restrict__ off,
                                                    int* __restrict__ cursor) {
    __shared__ int sums[1024];
    int t = threadIdx.x;
    int base = t * 20;
    int tmp[20];
    int s = 0;
#pragma unroll
    for (int i = 0; i < 20; ++i) {
        int idx = base + i;
        int v = (idx < N_NODES) ? deg[idx] : 0;
        tmp[i] = s;
        s += v;
    }
    sums[t] = s;
    __syncthreads();
    for (int st = 1; st < 1024; st <<= 1) {
        int v = (t >= st) ? sums[t - st] : 0;
        __syncthreads();
        sums[t] += v;
        __syncthreads();
    }
    int bsum = (t == 0) ? 0 : sums[t - 1];
#pragma unroll
    for (int i = 0; i < 20; ++i) {
        int idx = base + i;
        if (idx < N_NODES) {
            int v = bsum + tmp[i];
            off[idx] = v;
            cursor[idx] = v;
        }
    }
    if (t == 1023) off[N_NODES] = sums[1023];
}

__global__ void scatter_kernel(const int* __restrict__ ei,
                               int* __restrict__ cursor, int* __restrict__ csr) {
    int e = blockIdx.x * 256 + threadIdx.x;
    if (e >= ET) return;
    int s, d;
    if (e < E_EDGES) { s = ei[e]; d = ei[E_EDGES + e]; }
    else             { s = d = e - E_EDGES; }
    int pos = atomicAdd(&cursor[d], 1);
    csr[pos] = s;
}

// ---------------------------------------------------------------------------
// dots for layer 0 (from bf16 xb0). 32 nodes/block, 8 threads per node.
__global__ __launch_bounds__(256) void dots_kernel(const ushort_t* __restrict__ xb,
                                                   const float* __restrict__ wtS,
                                                   const float* __restrict__ wtD,
                                                   float* __restrict__ aS,
                                                   float* __restrict__ aD) {
    __shared__ float ls[4][128], ld_[4][128];
    int t = threadIdx.x;
    for (int i = t; i < 512; i += 256) {
        ls[i >> 7][i & 127] = wtS[i];
        ld_[i >> 7][i & 127] = wtD[i];
    }
    __syncthreads();
    int n = blockIdx.x * 32 + (t >> 3);
    int p = t & 7;
    const uint_t* xr = (const uint_t*)xb + (size_t)n * 64 + p * 8;
    float pS[4] = {0.f, 0.f, 0.f, 0.f}, pD[4] = {0.f, 0.f, 0.f, 0.f};
#pragma unroll
    for (int j = 0; j < 8; ++j) {
        uint_t u = xr[j];
        float f0 = bflo(u), f1 = bfhi(u);
        int d = p * 16 + j * 2;
#pragma unroll
        for (int h = 0; h < 4; ++h) {
            pS[h] = fmaf(f0, ls[h][d], fmaf(f1, ls[h][d + 1], pS[h]));
            pD[h] = fmaf(f0, ld_[h][d], fmaf(f1, ld_[h][d + 1], pD[h]));
        }
    }
#pragma unroll
    for (int st = 1; st < 8; st <<= 1) {
#pragma unroll
        for (int h = 0; h < 4; ++h) {
            pS[h] += __shfl_xor(pS[h], st);
            pD[h] += __shfl_xor(pD[h], st);
        }
    }
    if (p == 0) {
        *(float4*)(aS + (size_t)n * 4) = make_float4(pS[0], pS[1], pS[2], pS[3]);
        *(float4*)(aD + (size_t)n * 4) = make_float4(pD[0], pD[1], pD[2], pD[3]);
    }
}

// ---------------------------------------------------------------------------
// FUSED LAYER, 16 KB LDS. Phase A: EDGE-PARALLEL gather — lane = (eg,dl),
// eg in [0,4) edge group, dl in [0,16) dim group (8 dims each). 4 edges in
// flight per wave, no readlane broadcasts; cross-group reduce at the end.
// Phase B: 8-wave MFMA GEMM 16x512 @ 512x128 + residual + relu + fused dots.
__global__ __launch_bounds__(512) void gat_layer(const uint_t* __restrict__ xb2_cur,
                                                 const float* __restrict__ aS_cur,
                                                 const float* __restrict__ aD_cur,
                                                 const int* __restrict__ off,
                                                 const int* __restrict__ csr,
                                                 const ushort_t* __restrict__ Bp,
                                                 const float* __restrict__ bias,
                                                 const float* __restrict__ x_cur,
                                                 float* __restrict__ x_next,
                                                 ushort_t* __restrict__ xb_next,
                                                 const float* __restrict__ wtS,
                                                 const float* __restrict__ wtD,
                                                 float* __restrict__ aS_next,
                                                 float* __restrict__ aD_next,
                                                 int do_dots) {
    __shared__ ushort_t U_lds[LNODES][512];   // 16384 B

    int t = threadIdx.x;
    int w = t >> 6, l = t & 63;
    int eg = l >> 4, dl = l & 15;
    int n0 = blockIdx.x * LNODES;
    const uint4* xb4 = (const uint4*)xb2_cur;   // row = 16 uint4

    // ---------------- phase A: aggregation, 2 nodes per wave ----------------
    for (int it = 0; it < 2; ++it) {
        int row = w * 2 + it;
        int n = n0 + row;
        int beg = off[n];
        int deg = off[n + 1] - beg;

        float4 adv = *(const float4*)(aD_cur + (size_t)n * 4);

        // max pass: all 64 lanes stride over edges
        float4 smax = make_float4(-1e30f, -1e30f, -1e30f, -1e30f);
        for (int i = l; i < deg; i += 64) {
            int s = csr[beg + i];
            float4 a = *(const float4*)(aS_cur + (size_t)s * 4);
            smax.x = fmaxf(smax.x, a.x);
            smax.y = fmaxf(smax.y, a.y);
            smax.z = fmaxf(smax.z, a.z);
            smax.w = fmaxf(smax.w, a.w);
        }
#pragma unroll
        for (int st = 1; st < 64; st <<= 1) {
            smax.x = fmaxf(smax.x, __shfl_xor(smax.x, st));
            smax.y = fmaxf(smax.y, __shfl_xor(smax.y, st));
            smax.z = fmaxf(smax.z, __shfl_xor(smax.z, st));
            smax.w = fmaxf(smax.w, __shfl_xor(smax.w, st));
        }
        float e;
        e = smax.x + adv.x; float m0 = e > 0.f ? e : NEG_SLOPE * e;
        e = smax.y + adv.y; float m1 = e > 0.f ? e : NEG_SLOPE * e;
        e = smax.z + adv.z; float m2 = e > 0.f ? e : NEG_SLOPE * e;
        e = smax.w + adv.w; float m3 = e > 0.f ? e : NEG_SLOPE * e;

        // edge-parallel gather: edge c0+eg handled by 16 dl-lanes
        float a0[8], a1[8], a2[8], a3[8];   // acc per head, 8 dims each
#pragma unroll
        for (int d = 0; d < 8; ++d) { a0[d] = 0.f; a1[d] = 0.f; a2[d] = 0.f; a3[d] = 0.f; }
        float4 zac = make_float4(0.f, 0.f, 0.f, 0.f);

        for (int c0 = 0; c0 < deg; c0 += 4) {
            int ei_ = c0 + eg;
            if (ei_ < deg) {
                int s = csr[beg + ei_];                       // 16-lane broadcast
                float4 a = *(const float4*)(aS_cur + (size_t)s * 4);
                float w0, w1, w2, w3;
                e = a.x + adv.x; e = e > 0.f ? e : NEG_SLOPE * e; w0 = __expf(e - m0);
                e = a.y + adv.y; e = e > 0.f ? e : NEG_SLOPE * e; w1 = __expf(e - m1);
                e = a.z + adv.z; e = e > 0.f ? e : NEG_SLOPE * e; w2 = __expf(e - m2);
                e = a.w + adv.w; e = e > 0.f ? e : NEG_SLOPE * e; w3 = __expf(e - m3);
                zac.x += w0; zac.y += w1; zac.z += w2; zac.w += w3;
                uint4 xv = xb4[(size_t)s * 16 + dl];          // 8 dims of src row
                float f[8];
                f[0] = bflo(xv.x); f[1] = bfhi(xv.x);
                f[2] = bflo(xv.y); f[3] = bfhi(xv.y);
                f[4] = bflo(xv.z); f[5] = bfhi(xv.z);
                f[6] = bflo(xv.w); f[7] = bfhi(xv.w);
#pragma unroll
                for (int d = 0; d < 8; ++d) {
                    a0[d] = fmaf(w0, f[d], a0[d]);
                    a1[d] = fmaf(w1, f[d], a1[d]);
                    a2[d] = fmaf(w2, f[d], a2[d]);
                    a3[d] = fmaf(w3, f[d], a3[d]);
                }
            }
        }

        // reduce across the 4 edge groups (lane bits 4,5)
#pragma unroll
        for (int d = 0; d < 8; ++d) {
            a0[d] += __shfl_xor(a0[d], 16); a0[d] += __shfl_xor(a0[d], 32);
            a1[d] += __shfl_xor(a1[d], 16); a1[d] += __shfl_xor(a1[d], 32);
            a2[d] += __shfl_xor(a2[d], 16); a2[d] += __shfl_xor(a2[d], 32);
            a3[d] += __shfl_xor(a3[d], 16); a3[d] += __shfl_xor(a3[d], 32);
        }
        zac.x += __shfl_xor(zac.x, 16); zac.x += __shfl_xor(zac.x, 32);
        zac.y += __shfl_xor(zac.y, 16); zac.y += __shfl_xor(zac.y, 32);
        zac.z += __shfl_xor(zac.z, 16); zac.z += __shfl_xor(zac.z, 32);
        zac.w += __shfl_xor(zac.w, 16); zac.w += __shfl_xor(zac.w, 32);

        // lane (eg,dl) writes head eg, dims dl*8..dl*8+7 (static-select head)
        float zh = eg == 0 ? zac.x : eg == 1 ? zac.y : eg == 2 ? zac.z : zac.w;
        float iz = 1.f / zh;
        float o8[8];
#pragma unroll
        for (int d = 0; d < 8; ++d) {
            float v = eg == 0 ? a0[d] : eg == 1 ? a1[d] : eg == 2 ? a2[d] : a3[d];
            o8[d] = v * iz;
        }
        uint_t* U32 = (uint_t*)&U_lds[row][0];
        int swz = (row & 7) << 2;
#pragma unroll
        for (int u = 0; u < 4; ++u) {
            uint_t pk = (uint_t)f2bf(o8[2 * u]) | ((uint_t)f2bf(o8[2 * u + 1]) << 16);
            U32[eg * 64 + ((dl * 4 + u) ^ swz)] = pk;
        }
    }

    __syncthreads();

    // ---------------- phase B: GEMM 16x512 @ 512x128 ----------------
    int r16 = l & 15, g = l >> 4;
    int bn0 = w * 16;
    const ushort_t* bcol = Bp + (size_t)(bn0 + r16) * 512 + g * 8;
    int arow_sw = (r16 & 7) << 3;   // element-index XOR for ds reads

    f32x4 cacc = {};
#pragma unroll 4
    for (int k0 = 0; k0 < 512; k0 += 32) {
        bf16x8 a = *(const bf16x8*)&U_lds[r16][(k0 + g * 8) ^ arow_sw];
        bf16x8 bb = *(const bf16x8*)(bcol + k0);
        cacc = __builtin_amdgcn_mfma_f32_16x16x32_bf16(a, bb, cacc, 0, 0, 0);
    }

    // epilogue: residual + relu + store
    int col = bn0 + r16;
    float bia = bias[col];
    float nx[4];
#pragma unroll
    for (int r = 0; r < 4; ++r) {
        int rl = g * 4 + r;
        int row = n0 + rl;
        float v = 0.25f * cacc[r] + bia;
        v = v > 0.f ? v : 0.f;
        float nv = x_cur[(size_t)row * 128 + col] + v;
        x_next[(size_t)row * 128 + col] = nv;
        xb_next[(size_t)row * 128 + col] = f2bf(nv);
        nx[r] = nv;
    }

    // fused dots for next layer; scratch overlays U_lds (dead after k-loop)
    if (do_dots) {
        __syncthreads();   // ensure ALL waves finished reading U_lds
        float* ov = (float*)&U_lds[0][0];   // [0..511]=pS, [512..1023]=pD
        float wS[4], wD[4];
#pragma unroll
        for (int h = 0; h < 4; ++h) {
            wS[h] = wtS[h * 128 + col];
            wD[h] = wtD[h * 128 + col];
        }
#pragma unroll
        for (int r = 0; r < 4; ++r) {
            float sS[4], sD[4];
#pragma unroll
            for (int h = 0; h < 4; ++h) {
                sS[h] = nx[r] * wS[h];
                sD[h] = nx[r] * wD[h];
            }
#pragma unroll
            for (int st = 1; st < 16; st <<= 1)
#pragma unroll
                for (int h = 0; h < 4; ++h) {
                    sS[h] += __shfl_xor(sS[h], st);
                    sD[h] += __shfl_xor(sD[h], st);
                }
            if (r16 == 0) {
                int rl = g * 4 + r;
#pragma unroll
                for (int h = 0; h < 4; ++h) {
                    ov[(w * 16 + rl) * 4 + h] = sS[h];
                    ov[512 + (w * 16 + rl) * 4 + h] = sD[h];
                }
            }
        }
        __syncthreads();
        if (t < 64) {
            int rl = t >> 2, h = t & 3;
            int row = n0 + rl;
            float ssum = 0.f, dsum = 0.f;
#pragma unroll
            for (int ww = 0; ww < 8; ++ww) {
                ssum += ov[(ww * 16 + rl) * 4 + h];
                dsum += ov[512 + (ww * 16 + rl) * 4 + h];
            }
            aS_next[(size_t)row * 4 + h] = ssum;
            aD_next[(size_t)row * 4 + h] = dsum;
        }
    }
}

// ---------------------------------------------------------------------------
// Prediction heads (MFMA attack head + strided vuln dot)
__global__ __launch_bounds__(256) void pred_kernel(const float* __restrict__ x,
                                                   const ushort_t* __restrict__ xb,
                                                   const ushort_t* __restrict__ W1p,
                                                   const float* __restrict__ b1,
                                                   const float* __restrict__ W2,
                                                   const float* __restrict__ b2,
                                                   const float* __restrict__ vW,
                                                   const float* __restrict__ vb,
                                                   float* __restrict__ out) {
    int t = threadIdx.x;
    int lane = t & 63, w = t >> 6;
    int wr = w >> 1, wc = w & 1;
    int bm0 = blockIdx.x * 64 + wr * 32;
    int bn0 = wc * 32;
    int r16 = lane & 15, g = lane >> 4;

    const ushort_t* arow = xb + (size_t)(bm0 + r16) * 128 + g * 8;
    const ushort_t* bcol = W1p + (size_t)(bn0 + r16) * 128 + g * 8;

    f32x4 acc[2][2] = {};
#pragma unroll
    for (int k0 = 0; k0 < 128; k0 += 32) {
        bf16x8 a0 = *(const bf16x8*)(arow + k0);
        bf16x8 a1 = *(const bf16x8*)(arow + 16 * 128 + k0);
        bf16x8 b0 = *(const bf16x8*)(bcol + k0);
        bf16x8 b1 = *(const bf16x8*)(bcol + 16 * 128 + k0);
        acc[0][0] = __builtin_amdgcn_mfma_f32_16x16x32_bf16(a0, b0, acc[0][0], 0, 0, 0);
        acc[0][1] = __builtin_amdgcn_mfma_f32_16x16x32_bf16(a0, b1, acc[0][1], 0, 0, 0);
        acc[1][0] = __builtin_amdgcn_mfma_f32_16x16x32_bf16(a1, b0, acc[1][0], 0, 0, 0);
        acc[1][1] = __builtin_amdgcn_mfma_f32_16x16x32_bf16(a1, b1, acc[1][1], 0, 0, 0);
    }

    __shared__ float pa[2][64];
    float b1c[2] = {b1[bn0 + r16], b1[bn0 + 16 + r16]};
    float w2c[2] = {W2[bn0 + r16], W2[bn0 + 16 + r16]};
#pragma unroll
    for (int fm = 0; fm < 2; ++fm)
#pragma unroll
        for (int r = 0; r < 4; ++r) {
            float h10 = acc[fm][0][r] + b1c[0]; h10 = h10 > 0.f ? h10 : 0.f;
            float h11 = acc[fm][1][r] + b1c[1]; h11 = h11 > 0.f ? h11 : 0.f;
            float s = h10 * w2c[0] + h11 * w2c[1];
#pragma unroll
            for (int st = 1; st < 16; st <<= 1) s += __shfl_xor(s, st);
            if (r16 == 0) pa[wc][wr * 32 + fm * 16 + g * 4 + r] = s;
        }
    __syncthreads();
    if (t < 64) {
        int row = blockIdx.x * 64 + t;
        if (row < N_NODES) {
            float pre = pa[0][t] + pa[1][t] + b2[0];
            out[row] = 1.f / (1.f + __expf(-pre));
        }
    }
    int vrow = blockIdx.x * 64 + w * 16 + (lane >> 2);
    int q = lane & 3;
    if (vrow < N_NODES) {
        const float* xr = x + (size_t)vrow * 128 + q * 32;
        float s = 0.f;
#pragma unroll
        for (int j = 0; j < 32; ++j) s = fmaf(xr[j], vW[q * 32 + j], s);
        s += __shfl_xor(s, 1);
        s += __shfl_xor(s, 2);
        if (q == 0)
            out[N_NODES + vrow] = 1.f / (1.f + __expf(-(s + vb[0])));
    }
}

// ---------------------------------------------------------------------------
extern "C" void kernel_launch(void* const* d_in, const int* in_sizes, int n_in,
                              void* d_out, int out_size, void* d_ws, size_t ws_size,
                              hipStream_t stream) {
    const float* nf    = (const float*)d_in[0];
    const int*   ei    = (const int*)d_in[1];
    const float* encW  = (const float*)d_in[2];
    const float* encb  = (const float*)d_in[3];
    const float* lin   = (const float*)d_in[4];
    const float* attS  = (const float*)d_in[5];
    const float* attD  = (const float*)d_in[6];
    const float* gbias = (const float*)d_in[7];
    const float* W1    = (const float*)d_in[8];
    const float* b1    = (const float*)d_in[9];
    const float* W2    = (const float*)d_in[10];
    const float* b2    = (const float*)d_in[11];
    const float* vW    = (const float*)d_in[12];
    const float* vb    = (const float*)d_in[13];
    float* out = (float*)d_out;

    char* ws = (char*)d_ws;
    size_t o = 0;
    auto alloc = [&](size_t bytes) {
        void* p = ws + o;
        o += (bytes + 255) & ~(size_t)255;
        return p;
    };
    float* x0     = (float*)alloc((size_t)N_PAD * 128 * 4);
    float* x1     = (float*)alloc((size_t)N_PAD * 128 * 4);
    ushort_t* xb0 = (ushort_t*)alloc((size_t)N_PAD * 128 * 2);
    ushort_t* xb1 = (ushort_t*)alloc((size_t)N_PAD * 128 * 2);
    ushort_t* Bp  = (ushort_t*)alloc((size_t)3 * 128 * 512 * 2);
    ushort_t* W1p = (ushort_t*)alloc((size_t)64 * 128 * 2);
    float* wtS    = (float*)alloc((size_t)3 * 512 * 4);
    float* wtD    = (float*)alloc((size_t)3 * 512 * 4);
    float* aS0    = (float*)alloc((size_t)N_NODES * 4 * 4);
    float* aD0    = (float*)alloc((size_t)N_NODES * 4 * 4);
    float* aS1    = (float*)alloc((size_t)N_NODES * 4 * 4);
    float* aD1    = (float*)alloc((size_t)N_NODES * 4 * 4);
    int* deg      = (int*)alloc((size_t)N_NODES * 4);
    int* cursor   = (int*)alloc((size_t)N_NODES * 4);
    int* offs     = (int*)alloc((size_t)(N_NODES + 1) * 4);
    int* csr      = (int*)alloc((size_t)ET * 4);

    const int HIST_BLOCKS = (ET + 255) / 256;

    pack_all<<<96, 256, 0, stream>>>(lin, attS, attD, W1, Bp, wtS, wtD, W1p, deg);
    enc_hist<<<ENC_BLOCKS + HIST_BLOCKS, 256, 0, stream>>>(nf, encW, encb, ei, x0, xb0, deg);
    scan_kernel<<<1, 1024, 0, stream>>>(deg, offs, cursor);
    scatter_kernel<<<HIST_BLOCKS, 256, 0, stream>>>(ei, cursor, csr);
    dots_kernel<<<N_NODES / 32, 256, 0, stream>>>(xb0, wtS, wtD, aS0, aD0);

    float*    xc[2]  = {x0, x1};
    ushort_t* xbc[2] = {xb0, xb1};
    float*    aSc[2] = {aS0, aS1};
    float*    aDc[2] = {aD0, aD1};
    for (int l = 0; l < 3; ++l) {
        int ci = l & 1, ni = ci ^ 1;
        int dd = (l < 2) ? 1 : 0;
        gat_layer<<<N_NODES / LNODES, 512, 0, stream>>>(
            (const uint_t*)xbc[ci], aSc[ci], aDc[ci], offs, csr,
            Bp + (size_t)l * 128 * 512, gbias + (size_t)l * 128,
            xc[ci], xc[ni], xbc[ni],
            wtS + (size_t)(l + 1 < 3 ? l + 1 : 0) * 512,
            wtD + (size_t)(l + 1 < 3 ? l + 1 : 0) * 512,
            aSc[ni], aDc[ni], dd);
    }
    pred_kernel<<<N_PAD / 64, 256, 0, stream>>>(x1, xb1, W1p, b1, W2, b2, vW, vb, out);
}

// Round 11
// 322.464 us; speedup vs baseline: 1.0100x; 1.0100x over previous
//
#include <hip/hip_runtime.h>

#define N_NODES 20000
#define N_PAD 20032
#define F_IN 64
#define HID 128
#define HEADS 4
#define E_EDGES 320000
#define ET (E_EDGES + N_NODES)   // + self loops
#define NEG_SLOPE 0.2f
#define LNODES 16                // nodes per gat_layer block

typedef unsigned short ushort_t;
typedef unsigned int uint_t;

using bf16x8 = __attribute__((ext_vector_type(8))) short;
using f32x4  = __attribute__((ext_vector_type(4))) float;

__device__ __forceinline__ ushort_t f2bf(float f) {
    union { float f; uint_t u; } v; v.f = f;
    uint_t r = v.u + 0x7fffu + ((v.u >> 16) & 1u);   // round-to-nearest-even
    return (ushort_t)(r >> 16);
}
__device__ __forceinline__ float bflo(uint_t w) {
    union { uint_t u; float f; } v; v.u = w << 16; return v.f;
}
__device__ __forceinline__ float bfhi(uint_t w) {
    union { uint_t u; float f; } v; v.u = w & 0xffff0000u; return v.f;
}
__device__ __forceinline__ uint_t pk2(float a, float b) {
    return (uint_t)f2bf(a) | ((uint_t)f2bf(b) << 16);
}

// ---------------------------------------------------------------------------
// ONE pack kernel: Bp (W-bar bf16), wtS/wtD (f32), W1p (bf16), deg clear.
__global__ __launch_bounds__(256) void pack_all(const float* __restrict__ lin,
                                                const float* __restrict__ attS,
                                                const float* __restrict__ attD,
                                                const float* __restrict__ W1,
                                                ushort_t* __restrict__ Bp,
                                                float* __restrict__ wtS,
                                                float* __restrict__ wtD,
                                                ushort_t* __restrict__ W1p,
                                                int* __restrict__ deg) {
    int idx = blockIdx.x * 256 + threadIdx.x;
    if (idx < N_NODES) deg[idx] = 0;

    {   // job A: Bp[l][col][kk] = lin[l][kk&127][(kk>>7)*128 + col]
        int l = idx / 8192;
        int rem = idx % 8192;
        int col = rem / 64, kg = rem % 64;
        const float* W = lin + (size_t)l * 128 * 512;
        int h = kg >> 4;
        int kbase = (kg & 15) * 8;
        ushort_t tmp[8];
#pragma unroll
        for (int j = 0; j < 8; ++j)
            tmp[j] = f2bf(W[(size_t)(kbase + j) * 512 + h * 128 + col]);
        *(uint4*)(Bp + ((size_t)(l * 128 + col)) * 512 + kg * 8) = *(const uint4*)tmp;
    }

    if (idx < 1536) {   // job B: w-tilde
        int l = idx / 512;
        int rem = idx % 512;
        int h = rem >> 7, k = rem & 127;
        const float* W = lin + (size_t)l * 128 * 512 + (size_t)k * 512 + h * 128;
        const float* as = attS + (size_t)l * 512 + h * 128;
        const float* ad = attD + (size_t)l * 512 + h * 128;
        float ss = 0.f, sd = 0.f;
        for (int d = 0; d < 128; ++d) {
            float w = W[d];
            ss = fmaf(w, as[d], ss);
            sd = fmaf(w, ad[d], sd);
        }
        wtS[idx] = ss;
        wtD[idx] = sd;
    }

    if (idx < 1024) {   // job C: W1p
        int col = idx >> 4, kg = idx & 15;
        ushort_t tmp[8];
#pragma unroll
        for (int j = 0; j < 8; ++j)
            tmp[j] = f2bf(W1[(size_t)(kg * 8 + j) * 64 + col]);
        *(uint4*)(W1p + (size_t)col * 128 + kg * 8) = *(const uint4*)tmp;
    }
}

// ---------------------------------------------------------------------------
// Fused encoder + degree histogram.
#define ENC_BLOCKS 1250
__global__ __launch_bounds__(256) void enc_hist(const float* __restrict__ nf,
                                                const float* __restrict__ W,
                                                const float* __restrict__ b,
                                                const int* __restrict__ ei,
                                                float* __restrict__ x,
                                                ushort_t* __restrict__ xb,
                                                int* __restrict__ deg) {
    int t = threadIdx.x;
    if (blockIdx.x < ENC_BLOCKS) {
        __shared__ float xs[16][64];
        int n0 = blockIdx.x * 16;
        ((float4*)&xs[0][0])[t] = ((const float4*)(nf + (size_t)n0 * 64))[t];
        __syncthreads();
        int c = t & 127, ng = t >> 7;
        float acc[8];
#pragma unroll
        for (int i = 0; i < 8; ++i) acc[i] = 0.f;
        for (int k = 0; k < 64; ++k) {
            float wv = W[k * 128 + c];
#pragma unroll
            for (int i = 0; i < 8; ++i) acc[i] = fmaf(xs[ng * 8 + i][k], wv, acc[i]);
        }
        float bias = b[c];
#pragma unroll
        for (int i = 0; i < 8; ++i) {
            float v = acc[i] + bias;
            v = v > 0.f ? v : 0.f;
            int row = n0 + ng * 8 + i;
            x[(size_t)row * 128 + c] = v;
            xb[(size_t)row * 128 + c] = f2bf(v);
        }
    } else {
        int e = (blockIdx.x - ENC_BLOCKS) * 256 + t;
        if (e < ET) {
            int d = (e < E_EDGES) ? ei[E_EDGES + e] : (e - E_EDGES);
            atomicAdd(&deg[d], 1);
        }
    }
}

// ---------------------------------------------------------------------------
__global__ __launch_bounds__(1024) void scan_kernel(const int* __restrict__ deg,
                                                    int* __restrict__ off,
                                                    int* __restrict__ cursor) {
    __shared__ int sums[1024];
    int t = threadIdx.x;
    int base = t * 20;
    int tmp[20];
    int s = 0;
#pragma unroll
    for (int i = 0; i < 20; ++i) {
        int idx = base + i;
        int v = (idx < N_NODES) ? deg[idx] : 0;
        tmp[i] = s;
        s += v;
    }
    sums[t] = s;
    __syncthreads();
    for (int st = 1; st < 1024; st <<= 1) {
        int v = (t >= st) ? sums[t - st] : 0;
        __syncthreads();
        sums[t] += v;
        __syncthreads();
    }
    int bsum = (t == 0) ? 0 : sums[t - 1];
#pragma unroll
    for (int i = 0; i < 20; ++i) {
        int idx = base + i;
        if (idx < N_NODES) {
            int v = bsum + tmp[i];
            off[idx] = v;
            cursor[idx] = v;
        }
    }
    if (t == 1023) off[N_NODES] = sums[1023];
}

__global__ void scatter_kernel(const int* __restrict__ ei,
                               int* __restrict__ cursor, int* __restrict__ csr) {
    int e = blockIdx.x * 256 + threadIdx.x;
    if (e >= ET) return;
    int s, d;
    if (e < E_EDGES) { s = ei[e]; d = ei[E_EDGES + e]; }
    else             { s = d = e - E_EDGES; }
    int pos = atomicAdd(&cursor[d], 1);
    csr[pos] = s;
}

// ---------------------------------------------------------------------------
// dots for layer 0 (from bf16 xb0). 32 nodes/block, 8 threads per node.
__global__ __launch_bounds__(256) void dots_kernel(const ushort_t* __restrict__ xb,
                                                   const float* __restrict__ wtS,
                                                   const float* __restrict__ wtD,
                                                   float* __restrict__ aS,
                                                   float* __restrict__ aD) {
    __shared__ float ls[4][128], ld_[4][128];
    int t = threadIdx.x;
    for (int i = t; i < 512; i += 256) {
        ls[i >> 7][i & 127] = wtS[i];
        ld_[i >> 7][i & 127] = wtD[i];
    }
    __syncthreads();
    int n = blockIdx.x * 32 + (t >> 3);
    int p = t & 7;
    const uint_t* xr = (const uint_t*)xb + (size_t)n * 64 + p * 8;
    float pS[4] = {0.f, 0.f, 0.f, 0.f}, pD[4] = {0.f, 0.f, 0.f, 0.f};
#pragma unroll
    for (int j = 0; j < 8; ++j) {
        uint_t u = xr[j];
        float f0 = bflo(u), f1 = bfhi(u);
        int d = p * 16 + j * 2;
#pragma unroll
        for (int h = 0; h < 4; ++h) {
            pS[h] = fmaf(f0, ls[h][d], fmaf(f1, ls[h][d + 1], pS[h]));
            pD[h] = fmaf(f0, ld_[h][d], fmaf(f1, ld_[h][d + 1], pD[h]));
        }
    }
#pragma unroll
    for (int st = 1; st < 8; st <<= 1) {
#pragma unroll
        for (int h = 0; h < 4; ++h) {
            pS[h] += __shfl_xor(pS[h], st);
            pD[h] += __shfl_xor(pD[h], st);
        }
    }
    if (p == 0) {
        *(float4*)(aS + (size_t)n * 4) = make_float4(pS[0], pS[1], pS[2], pS[3]);
        *(float4*)(aD + (size_t)n * 4) = make_float4(pD[0], pD[1], pD[2], pD[3]);
    }
}

// ---------------------------------------------------------------------------
// PHASE A (device fn): half-wave-per-node softmax gather into U_lds.
// lane = (hw, q): hw = which of the wave's 2 nodes, q = 0..31 covers the
// 32 edges of a chunk AND dims 4q..4q+3 of the gathered row (uint2/lane).
// chunk 0 (<=32 edges) fully register-cached: csr, aS, weights.
__device__ __forceinline__ void phaseA(int t, int n0,
                                       const uint2* __restrict__ xbv,
                                       const float* __restrict__ aS_cur,
                                       const float* __restrict__ aD_cur,
                                       const int* __restrict__ off,
                                       const int* __restrict__ csr,
                                       ushort_t (*U_lds)[512]) {
    int w = t >> 6, l = t & 63;
    int hw = l >> 5, q = l & 31;
    int row = w * 2 + hw;
    int n = n0 + row;
    int beg = off[n];
    int deg = off[n + 1] - beg;
    int base = hw << 5;

    float4 adv = *(const float4*)(aD_cur + (size_t)n * 4);

    // cached chunk 0
    int sl = 0;
    float4 av = make_float4(-1e30f, -1e30f, -1e30f, -1e30f);
    if (q < deg) {
        sl = csr[beg + q];
        av = *(const float4*)(aS_cur + (size_t)sl * 4);
    }
    float4 smax = av;
    for (int i = q + 32; i < deg; i += 32) {
        int s = csr[beg + i];
        float4 a = *(const float4*)(aS_cur + (size_t)s * 4);
        smax.x = fmaxf(smax.x, a.x); smax.y = fmaxf(smax.y, a.y);
        smax.z = fmaxf(smax.z, a.z); smax.w = fmaxf(smax.w, a.w);
    }
#pragma unroll
    for (int st = 1; st < 32; st <<= 1) {
        smax.x = fmaxf(smax.x, __shfl_xor(smax.x, st));
        smax.y = fmaxf(smax.y, __shfl_xor(smax.y, st));
        smax.z = fmaxf(smax.z, __shfl_xor(smax.z, st));
        smax.w = fmaxf(smax.w, __shfl_xor(smax.w, st));
    }
    float e;
    e = smax.x + adv.x; float m0 = e > 0.f ? e : NEG_SLOPE * e;
    e = smax.y + adv.y; float m1 = e > 0.f ? e : NEG_SLOPE * e;
    e = smax.z + adv.z; float m2 = e > 0.f ? e : NEG_SLOPE * e;
    e = smax.w + adv.w; float m3 = e > 0.f ? e : NEG_SLOPE * e;

    // weights for cached chunk
    float4 wv = make_float4(0.f, 0.f, 0.f, 0.f);
    if (q < deg) {
        e = av.x + adv.x; e = e > 0.f ? e : NEG_SLOPE * e; wv.x = __expf(e - m0);
        e = av.y + adv.y; e = e > 0.f ? e : NEG_SLOPE * e; wv.y = __expf(e - m1);
        e = av.z + adv.z; e = e > 0.f ? e : NEG_SLOPE * e; wv.z = __expf(e - m2);
        e = av.w + adv.w; e = e > 0.f ? e : NEG_SLOPE * e; wv.w = __expf(e - m3);
    }
    float4 zp = wv;

    float a0[4] = {0.f, 0.f, 0.f, 0.f};
    float a1[4] = {0.f, 0.f, 0.f, 0.f};
    float a2[4] = {0.f, 0.f, 0.f, 0.f};
    float a3[4] = {0.f, 0.f, 0.f, 0.f};

    int ce = min(deg, 32);
#pragma unroll 4
    for (int j = 0; j < ce; ++j) {
        int src = __shfl(sl, base + j);
        float w0 = __shfl(wv.x, base + j);
        float w1 = __shfl(wv.y, base + j);
        float w2 = __shfl(wv.z, base + j);
        float w3 = __shfl(wv.w, base + j);
        uint2 xv = xbv[(size_t)src * 32 + q];
        float f0 = bflo(xv.x), f1 = bfhi(xv.x), f2 = bflo(xv.y), f3 = bfhi(xv.y);
        a0[0] = fmaf(w0, f0, a0[0]); a0[1] = fmaf(w0, f1, a0[1]);
        a0[2] = fmaf(w0, f2, a0[2]); a0[3] = fmaf(w0, f3, a0[3]);
        a1[0] = fmaf(w1, f0, a1[0]); a1[1] = fmaf(w1, f1, a1[1]);
        a1[2] = fmaf(w1, f2, a1[2]); a1[3] = fmaf(w1, f3, a1[3]);
        a2[0] = fmaf(w2, f0, a2[0]); a2[1] = fmaf(w2, f1, a2[1]);
        a2[2] = fmaf(w2, f2, a2[2]); a2[3] = fmaf(w2, f3, a2[3]);
        a3[0] = fmaf(w3, f0, a3[0]); a3[1] = fmaf(w3, f1, a3[1]);
        a3[2] = fmaf(w3, f2, a3[2]); a3[3] = fmaf(w3, f3, a3[3]);
    }

    // rare: chunks beyond 32
    for (int c0 = 32; c0 < deg; c0 += 32) {
        int ce2 = min(32, deg - c0);
        int sl2 = 0;
        float4 wv2 = make_float4(0.f, 0.f, 0.f, 0.f);
        if (q < ce2) {
            sl2 = csr[beg + c0 + q];
            float4 a = *(const float4*)(aS_cur + (size_t)sl2 * 4);
            e = a.x + adv.x; e = e > 0.f ? e : NEG_SLOPE * e; wv2.x = __expf(e - m0);
            e = a.y + adv.y; e = e > 0.f ? e : NEG_SLOPE * e; wv2.y = __expf(e - m1);
            e = a.z + adv.z; e = e > 0.f ? e : NEG_SLOPE * e; wv2.z = __expf(e - m2);
            e = a.w + adv.w; e = e > 0.f ? e : NEG_SLOPE * e; wv2.w = __expf(e - m3);
            zp.x += wv2.x; zp.y += wv2.y; zp.z += wv2.z; zp.w += wv2.w;
        }
#pragma unroll 4
        for (int j = 0; j < ce2; ++j) {
            int src = __shfl(sl2, base + j);
            float w0 = __shfl(wv2.x, base + j);
            float w1 = __shfl(wv2.y, base + j);
            float w2 = __shfl(wv2.z, base + j);
            float w3 = __shfl(wv2.w, base + j);
            uint2 xv = xbv[(size_t)src * 32 + q];
            float f0 = bflo(xv.x), f1 = bfhi(xv.x), f2 = bflo(xv.y), f3 = bfhi(xv.y);
            a0[0] = fmaf(w0, f0, a0[0]); a0[1] = fmaf(w0, f1, a0[1]);
            a0[2] = fmaf(w0, f2, a0[2]); a0[3] = fmaf(w0, f3, a0[3]);
            a1[0] = fmaf(w1, f0, a1[0]); a1[1] = fmaf(w1, f1, a1[1]);
            a1[2] = fmaf(w1, f2, a1[2]); a1[3] = fmaf(w1, f3, a1[3]);
            a2[0] = fmaf(w2, f0, a2[0]); a2[1] = fmaf(w2, f1, a2[1]);
            a2[2] = fmaf(w2, f2, a2[2]); a2[3] = fmaf(w2, f3, a2[3]);
            a3[0] = fmaf(w3, f0, a3[0]); a3[1] = fmaf(w3, f1, a3[1]);
            a3[2] = fmaf(w3, f2, a3[2]); a3[3] = fmaf(w3, f3, a3[3]);
        }
    }

    // z reduce within half
#pragma unroll
    for (int st = 1; st < 32; st <<= 1) {
        zp.x += __shfl_xor(zp.x, st);
        zp.y += __shfl_xor(zp.y, st);
        zp.z += __shfl_xor(zp.z, st);
        zp.w += __shfl_xor(zp.w, st);
    }
    float iz0 = 1.f / zp.x, iz1 = 1.f / zp.y, iz2 = 1.f / zp.z, iz3 = 1.f / zp.w;

    // store: lane q -> dims 4q..4q+3 = uints 2q,2q+1 per head; XOR-swizzled
    uint_t* U32 = (uint_t*)&U_lds[row][0];
    int swz = (row & 7) << 2;
    int u0 = (2 * q) ^ swz, u1 = (2 * q + 1) ^ swz;
    U32[u0]        = pk2(a0[0] * iz0, a0[1] * iz0);
    U32[u1]        = pk2(a0[2] * iz0, a0[3] * iz0);
    U32[64 + u0]   = pk2(a1[0] * iz1, a1[1] * iz1);
    U32[64 + u1]   = pk2(a1[2] * iz1, a1[3] * iz1);
    U32[128 + u0]  = pk2(a2[0] * iz2, a2[1] * iz2);
    U32[128 + u1]  = pk2(a2[2] * iz2, a2[3] * iz2);
    U32[192 + u0]  = pk2(a3[0] * iz3, a3[1] * iz3);
    U32[192 + u1]  = pk2(a3[2] * iz3, a3[3] * iz3);
}

// ---------------------------------------------------------------------------
// PHASE B (device fn): 8-wave MFMA GEMM 16x512 @ 512x128 + residual + relu
// + optional fused dots (scratch overlays U_lds after the k-loop).
__device__ __forceinline__ void phaseB(int t, int n0,
                                       ushort_t (*U_lds)[512],
                                       const ushort_t* __restrict__ Bp,
                                       const float* __restrict__ bias,
                                       const float* __restrict__ x_cur,
                                       float* __restrict__ x_next,
                                       ushort_t* __restrict__ xb_next,
                                       const float* __restrict__ wtS,
                                       const float* __restrict__ wtD,
                                       float* __restrict__ aS_next,
                                       float* __restrict__ aD_next,
                                       int do_dots) {
    int w = t >> 6, l = t & 63;
    int r16 = l & 15, g = l >> 4;
    int bn0 = w * 16;
    const ushort_t* bcol = Bp + (size_t)(bn0 + r16) * 512 + g * 8;
    int arow_sw = (r16 & 7) << 3;

    f32x4 cacc = {};
#pragma unroll 4
    for (int k0 = 0; k0 < 512; k0 += 32) {
        bf16x8 a = *(const bf16x8*)&U_lds[r16][(k0 + g * 8) ^ arow_sw];
        bf16x8 bb = *(const bf16x8*)(bcol + k0);
        cacc = __builtin_amdgcn_mfma_f32_16x16x32_bf16(a, bb, cacc, 0, 0, 0);
    }

    int col = bn0 + r16;
    float bia = bias[col];
    float nx[4];
#pragma unroll
    for (int r = 0; r < 4; ++r) {
        int rl = g * 4 + r;
        int row = n0 + rl;
        float v = 0.25f * cacc[r] + bia;
        v = v > 0.f ? v : 0.f;
        float nv = x_cur[(size_t)row * 128 + col] + v;
        x_next[(size_t)row * 128 + col] = nv;
        xb_next[(size_t)row * 128 + col] = f2bf(nv);
        nx[r] = nv;
    }

    if (do_dots) {
        __syncthreads();
        float* ov = (float*)&U_lds[0][0];
        float wS[4], wD[4];
#pragma unroll
        for (int h = 0; h < 4; ++h) {
            wS[h] = wtS[h * 128 + col];
            wD[h] = wtD[h * 128 + col];
        }
#pragma unroll
        for (int r = 0; r < 4; ++r) {
            float sS[4], sD[4];
#pragma unroll
            for (int h = 0; h < 4; ++h) {
                sS[h] = nx[r] * wS[h];
                sD[h] = nx[r] * wD[h];
            }
#pragma unroll
            for (int st = 1; st < 16; st <<= 1)
#pragma unroll
                for (int h = 0; h < 4; ++h) {
                    sS[h] += __shfl_xor(sS[h], st);
                    sD[h] += __shfl_xor(sD[h], st);
                }
            if (r16 == 0) {
                int rl = g * 4 + r;
#pragma unroll
                for (int h = 0; h < 4; ++h) {
                    ov[(w * 16 + rl) * 4 + h] = sS[h];
                    ov[512 + (w * 16 + rl) * 4 + h] = sD[h];
                }
            }
        }
        __syncthreads();
        if (t < 64) {
            int rl = t >> 2, h = t & 3;
            int row = n0 + rl;
            float ssum = 0.f, dsum = 0.f;
#pragma unroll
            for (int ww = 0; ww < 8; ++ww) {
                ssum += ov[(ww * 16 + rl) * 4 + h];
                dsum += ov[512 + (ww * 16 + rl) * 4 + h];
            }
            aS_next[(size_t)row * 4 + h] = ssum;
            aD_next[(size_t)row * 4 + h] = dsum;
        }
    }
}

// ---------------------------------------------------------------------------
__global__ __launch_bounds__(512) void gat_layer(const uint2* __restrict__ xbv,
                                                 const float* __restrict__ aS_cur,
                                                 const float* __restrict__ aD_cur,
                                                 const int* __restrict__ off,
                                                 const int* __restrict__ csr,
                                                 const ushort_t* __restrict__ Bp,
                                                 const float* __restrict__ bias,
                                                 const float* __restrict__ x_cur,
                                                 float* __restrict__ x_next,
                                                 ushort_t* __restrict__ xb_next,
                                                 const float* __restrict__ wtS,
                                                 const float* __restrict__ wtD,
                                                 float* __restrict__ aS_next,
                                                 float* __restrict__ aD_next,
                                                 int do_dots) {
    __shared__ ushort_t U_lds[LNODES][512];
    int t = threadIdx.x;
    int n0 = blockIdx.x * LNODES;
    phaseA(t, n0, xbv, aS_cur, aD_cur, off, csr, U_lds);
    __syncthreads();
    phaseB(t, n0, U_lds, Bp, bias, x_cur, x_next, xb_next,
           wtS, wtD, aS_next, aD_next, do_dots);
}

// ---------------------------------------------------------------------------
// ABLATION PROBES (write only to scratch; run after pred_kernel)
__global__ __launch_bounds__(512) void probe_aggA(const uint2* __restrict__ xbv,
                                                  const float* __restrict__ aS_cur,
                                                  const float* __restrict__ aD_cur,
                                                  const int* __restrict__ off,
                                                  const int* __restrict__ csr,
                                                  uint_t* __restrict__ dump) {
    __shared__ ushort_t U_lds[LNODES][512];
    int t = threadIdx.x;
    int n0 = blockIdx.x * LNODES;
    phaseA(t, n0, xbv, aS_cur, aD_cur, off, csr, U_lds);
    __syncthreads();
    const uint_t* U32 = (const uint_t*)&U_lds[0][0];
    uint_t acc = 0;
#pragma unroll
    for (int i = 0; i < 8; ++i) acc += U32[t + i * 512];
    dump[blockIdx.x * 512 + t] = acc;
}

__global__ __launch_bounds__(512) void probe_gemmB(const ushort_t* __restrict__ Bp,
                                                   const float* __restrict__ bias,
                                                   const float* __restrict__ x_cur,
                                                   float* __restrict__ dx,
                                                   ushort_t* __restrict__ dxb,
                                                   const float* __restrict__ wtS,
                                                   const float* __restrict__ wtD,
                                                   float* __restrict__ daS,
                                                   float* __restrict__ daD) {
    __shared__ ushort_t U_lds[LNODES][512];
    int t = threadIdx.x;
    int n0 = blockIdx.x * LNODES;
    uint_t* U32 = (uint_t*)&U_lds[0][0];
#pragma unroll
    for (int i = 0; i < 8; ++i)
        U32[t + i * 512] = 0x3f803f80u + (uint_t)t + (uint_t)i;   // benign bf16 seeds
    __syncthreads();
    phaseB(t, n0, U_lds, Bp, bias, x_cur, dx, dxb, wtS, wtD, daS, daD, 1);
}

// ---------------------------------------------------------------------------
// Prediction heads (MFMA attack head + strided vuln dot)
__global__ __launch_bounds__(256) void pred_kernel(const float* __restrict__ x,
                                                   const ushort_t* __restrict__ xb,
                                                   const ushort_t* __restrict__ W1p,
                                                   const float* __restrict__ b1,
                                                   const float* __restrict__ W2,
                                                   const float* __restrict__ b2,
                                                   const float* __restrict__ vW,
                                                   const float* __restrict__ vb,
                                                   float* __restrict__ out) {
    int t = threadIdx.x;
    int lane = t & 63, w = t >> 6;
    int wr = w >> 1, wc = w & 1;
    int bm0 = blockIdx.x * 64 + wr * 32;
    int bn0 = wc * 32;
    int r16 = lane & 15, g = lane >> 4;

    const ushort_t* arow = xb + (size_t)(bm0 + r16) * 128 + g * 8;
    const ushort_t* bcol = W1p + (size_t)(bn0 + r16) * 128 + g * 8;

    f32x4 acc[2][2] = {};
#pragma unroll
    for (int k0 = 0; k0 < 128; k0 += 32) {
        bf16x8 a0 = *(const bf16x8*)(arow + k0);
        bf16x8 a1 = *(const bf16x8*)(arow + 16 * 128 + k0);
        bf16x8 b0 = *(const bf16x8*)(bcol + k0);
        bf16x8 b1 = *(const bf16x8*)(bcol + 16 * 128 + k0);
        acc[0][0] = __builtin_amdgcn_mfma_f32_16x16x32_bf16(a0, b0, acc[0][0], 0, 0, 0);
        acc[0][1] = __builtin_amdgcn_mfma_f32_16x16x32_bf16(a0, b1, acc[0][1], 0, 0, 0);
        acc[1][0] = __builtin_amdgcn_mfma_f32_16x16x32_bf16(a1, b0, acc[1][0], 0, 0, 0);
        acc[1][1] = __builtin_amdgcn_mfma_f32_16x16x32_bf16(a1, b1, acc[1][1], 0, 0, 0);
    }

    __shared__ float pa[2][64];
    float b1c[2] = {b1[bn0 + r16], b1[bn0 + 16 + r16]};
    float w2c[2] = {W2[bn0 + r16], W2[bn0 + 16 + r16]};
#pragma unroll
    for (int fm = 0; fm < 2; ++fm)
#pragma unroll
        for (int r = 0; r < 4; ++r) {
            float h10 = acc[fm][0][r] + b1c[0]; h10 = h10 > 0.f ? h10 : 0.f;
            float h11 = acc[fm][1][r] + b1c[1]; h11 = h11 > 0.f ? h11 : 0.f;
            float s = h10 * w2c[0] + h11 * w2c[1];
#pragma unroll
            for (int st = 1; st < 16; st <<= 1) s += __shfl_xor(s, st);
            if (r16 == 0) pa[wc][wr * 32 + fm * 16 + g * 4 + r] = s;
        }
    __syncthreads();
    if (t < 64) {
        int row = blockIdx.x * 64 + t;
        if (row < N_NODES) {
            float pre = pa[0][t] + pa[1][t] + b2[0];
            out[row] = 1.f / (1.f + __expf(-pre));
        }
    }
    int vrow = blockIdx.x * 64 + w * 16 + (lane >> 2);
    int q = lane & 3;
    if (vrow < N_NODES) {
        const float* xr = x + (size_t)vrow * 128 + q * 32;
        float s = 0.f;
#pragma unroll
        for (int j = 0; j < 32; ++j) s = fmaf(xr[j], vW[q * 32 + j], s);
        s += __shfl_xor(s, 1);
        s += __shfl_xor(s, 2);
        if (q == 0)
            out[N_NODES + vrow] = 1.f / (1.f + __expf(-(s + vb[0])));
    }
}

// ---------------------------------------------------------------------------
extern "C" void kernel_launch(void* const* d_in, const int* in_sizes, int n_in,
                              void* d_out, int out_size, void* d_ws, size_t ws_size,
                              hipStream_t stream) {
    const float* nf    = (const float*)d_in[0];
    const int*   ei    = (const int*)d_in[1];
    const float* encW  = (const float*)d_in[2];
    const float* encb  = (const float*)d_in[3];
    const float* lin   = (const float*)d_in[4];
    const float* attS  = (const float*)d_in[5];
    const float* attD  = (const float*)d_in[6];
    const float* gbias = (const float*)d_in[7];
    const float* W1    = (const float*)d_in[8];
    const float* b1    = (const float*)d_in[9];
    const float* W2    = (const float*)d_in[10];
    const float* b2    = (const float*)d_in[11];
    const float* vW    = (const float*)d_in[12];
    const float* vb    = (const float*)d_in[13];
    float* out = (float*)d_out;

    char* ws = (char*)d_ws;
    size_t o = 0;
    auto alloc = [&](size_t bytes) {
        void* p = ws + o;
        o += (bytes + 255) & ~(size_t)255;
        return p;
    };
    float* x0     = (float*)alloc((size_t)N_PAD * 128 * 4);
    float* x1     = (float*)alloc((size_t)N_PAD * 128 * 4);
    ushort_t* xb0 = (ushort_t*)alloc((size_t)N_PAD * 128 * 2);
    ushort_t* xb1 = (ushort_t*)alloc((size_t)N_PAD * 128 * 2);
    ushort_t* Bp  = (ushort_t*)alloc((size_t)3 * 128 * 512 * 2);
    ushort_t* W1p = (ushort_t*)alloc((size_t)64 * 128 * 2);
    float* wtS    = (float*)alloc((size_t)3 * 512 * 4);
    float* wtD    = (float*)alloc((size_t)3 * 512 * 4);
    float* aS0    = (float*)alloc((size_t)N_NODES * 4 * 4);
    float* aD0    = (float*)alloc((size_t)N_NODES * 4 * 4);
    float* aS1    = (float*)alloc((size_t)N_NODES * 4 * 4);
    float* aD1    = (float*)alloc((size_t)N_NODES * 4 * 4);
    int* deg      = (int*)alloc((size_t)N_NODES * 4);
    int* cursor   = (int*)alloc((size_t)N_NODES * 4);
    int* offs     = (int*)alloc((size_t)(N_NODES + 1) * 4);
    int* csr      = (int*)alloc((size_t)ET * 4);
    // probe scratch
    uint_t* pdump = (uint_t*)alloc((size_t)1250 * 512 * 4);
    float* dx     = (float*)alloc((size_t)N_PAD * 128 * 4);
    ushort_t* dxb = (ushort_t*)alloc((size_t)N_PAD * 128 * 2);
    float* daS    = (float*)alloc((size_t)N_NODES * 4 * 4);
    float* daD    = (float*)alloc((size_t)N_NODES * 4 * 4);

    const int HIST_BLOCKS = (ET + 255) / 256;

    pack_all<<<96, 256, 0, stream>>>(lin, attS, attD, W1, Bp, wtS, wtD, W1p, deg);
    enc_hist<<<ENC_BLOCKS + HIST_BLOCKS, 256, 0, stream>>>(nf, encW, encb, ei, x0, xb0, deg);
    scan_kernel<<<1, 1024, 0, stream>>>(deg, offs, cursor);
    scatter_kernel<<<HIST_BLOCKS, 256, 0, stream>>>(ei, cursor, csr);
    dots_kernel<<<N_NODES / 32, 256, 0, stream>>>(xb0, wtS, wtD, aS0, aD0);

    float*    xc[2]  = {x0, x1};
    ushort_t* xbc[2] = {xb0, xb1};
    float*    aSc[2] = {aS0, aS1};
    float*    aDc[2] = {aD0, aD1};
    for (int l = 0; l < 3; ++l) {
        int ci = l & 1, ni = ci ^ 1;
        int dd = (l < 2) ? 1 : 0;
        gat_layer<<<N_NODES / LNODES, 512, 0, stream>>>(
            (const uint2*)xbc[ci], aSc[ci], aDc[ci], offs, csr,
            Bp + (size_t)l * 128 * 512, gbias + (size_t)l * 128,
            xc[ci], xc[ni], xbc[ni],
            wtS + (size_t)(l + 1 < 3 ? l + 1 : 0) * 512,
            wtD + (size_t)(l + 1 < 3 ? l + 1 : 0) * 512,
            aSc[ni], aDc[ni], dd);
    }
    pred_kernel<<<N_PAD / 64, 256, 0, stream>>>(x1, xb1, W1p, b1, W2, b2, vW, vb, out);

    // ---- ablation probes (scratch-only writes; timing read from rocprof) ----
    probe_aggA<<<N_NODES / LNODES, 512, 0, stream>>>((const uint2*)xb0, aS0, aD0,
                                                     offs, csr, pdump);
    probe_gemmB<<<N_NODES / LNODES, 512, 0, stream>>>(Bp, gbias, x0, dx, dxb,
                                                      wtS, wtD, daS, daD);
}

// Round 12
// 277.478 us; speedup vs baseline: 1.1737x; 1.1621x over previous
//
#include <hip/hip_runtime.h>

#define N_NODES 20000
#define N_PAD 20032
#define F_IN 64
#define HID 128
#define HEADS 4
#define E_EDGES 320000
#define ET (E_EDGES + N_NODES)   // + self loops
#define NEG_SLOPE 0.2f
#define LNODES 16                // nodes per gat_layer block

typedef unsigned short ushort_t;
typedef unsigned int uint_t;

using bf16x8 = __attribute__((ext_vector_type(8))) short;
using f32x4  = __attribute__((ext_vector_type(4))) float;

__device__ __forceinline__ ushort_t f2bf(float f) {
    union { float f; uint_t u; } v; v.f = f;
    uint_t r = v.u + 0x7fffu + ((v.u >> 16) & 1u);   // round-to-nearest-even
    return (ushort_t)(r >> 16);
}
__device__ __forceinline__ float bflo(uint_t w) {
    union { uint_t u; float f; } v; v.u = w << 16; return v.f;
}
__device__ __forceinline__ float bfhi(uint_t w) {
    union { uint_t u; float f; } v; v.u = w & 0xffff0000u; return v.f;
}
__device__ __forceinline__ uint_t pk2(float a, float b) {
    return (uint_t)f2bf(a) | ((uint_t)f2bf(b) << 16);
}
// monotone float<->uint key for atomicMax on floats
__device__ __forceinline__ uint_t fkey(float f) {
    uint_t u = __float_as_uint(f);
    return (u & 0x80000000u) ? ~u : (u | 0x80000000u);
}
__device__ __forceinline__ float keyf(uint_t k) {
    uint_t u = (k & 0x80000000u) ? (k & 0x7fffffffu) : ~k;
    return __uint_as_float(u);
}

// ---------------------------------------------------------------------------
// ONE pack kernel: Bp (W-bar bf16), wtS/wtD (f32), W1p (bf16), deg clear,
// gmax key init (3 layers x 4 heads).
__global__ __launch_bounds__(256) void pack_all(const float* __restrict__ lin,
                                                const float* __restrict__ attS,
                                                const float* __restrict__ attD,
                                                const float* __restrict__ W1,
                                                ushort_t* __restrict__ Bp,
                                                float* __restrict__ wtS,
                                                float* __restrict__ wtD,
                                                ushort_t* __restrict__ W1p,
                                                int* __restrict__ deg,
                                                uint_t* __restrict__ gmaxK) {
    int idx = blockIdx.x * 256 + threadIdx.x;
    if (idx < N_NODES) deg[idx] = 0;
    if (idx < 12) gmaxK[idx] = 0u;

    {   // job A: Bp[l][col][kk] = lin[l][kk&127][(kk>>7)*128 + col]
        int l = idx / 8192;
        int rem = idx % 8192;
        int col = rem / 64, kg = rem % 64;
        const float* W = lin + (size_t)l * 128 * 512;
        int h = kg >> 4;
        int kbase = (kg & 15) * 8;
        ushort_t tmp[8];
#pragma unroll
        for (int j = 0; j < 8; ++j)
            tmp[j] = f2bf(W[(size_t)(kbase + j) * 512 + h * 128 + col]);
        *(uint4*)(Bp + ((size_t)(l * 128 + col)) * 512 + kg * 8) = *(const uint4*)tmp;
    }

    if (idx < 1536) {   // job B: w-tilde
        int l = idx / 512;
        int rem = idx % 512;
        int h = rem >> 7, k = rem & 127;
        const float* W = lin + (size_t)l * 128 * 512 + (size_t)k * 512 + h * 128;
        const float* as = attS + (size_t)l * 512 + h * 128;
        const float* ad = attD + (size_t)l * 512 + h * 128;
        float ss = 0.f, sd = 0.f;
        for (int d = 0; d < 128; ++d) {
            float w = W[d];
            ss = fmaf(w, as[d], ss);
            sd = fmaf(w, ad[d], sd);
        }
        wtS[idx] = ss;
        wtD[idx] = sd;
    }

    if (idx < 1024) {   // job C: W1p
        int col = idx >> 4, kg = idx & 15;
        ushort_t tmp[8];
#pragma unroll
        for (int j = 0; j < 8; ++j)
            tmp[j] = f2bf(W1[(size_t)(kg * 8 + j) * 64 + col]);
        *(uint4*)(W1p + (size_t)col * 128 + kg * 8) = *(const uint4*)tmp;
    }
}

// ---------------------------------------------------------------------------
// Fused encoder + degree histogram.
#define ENC_BLOCKS 1250
__global__ __launch_bounds__(256) void enc_hist(const float* __restrict__ nf,
                                                const float* __restrict__ W,
                                                const float* __restrict__ b,
                                                const int* __restrict__ ei,
                                                float* __restrict__ x,
                                                ushort_t* __restrict__ xb,
                                                int* __restrict__ deg) {
    int t = threadIdx.x;
    if (blockIdx.x < ENC_BLOCKS) {
        __shared__ float xs[16][64];
        int n0 = blockIdx.x * 16;
        ((float4*)&xs[0][0])[t] = ((const float4*)(nf + (size_t)n0 * 64))[t];
        __syncthreads();
        int c = t & 127, ng = t >> 7;
        float acc[8];
#pragma unroll
        for (int i = 0; i < 8; ++i) acc[i] = 0.f;
        for (int k = 0; k < 64; ++k) {
            float wv = W[k * 128 + c];
#pragma unroll
            for (int i = 0; i < 8; ++i) acc[i] = fmaf(xs[ng * 8 + i][k], wv, acc[i]);
        }
        float bias = b[c];
#pragma unroll
        for (int i = 0; i < 8; ++i) {
            float v = acc[i] + bias;
            v = v > 0.f ? v : 0.f;
            int row = n0 + ng * 8 + i;
            x[(size_t)row * 128 + c] = v;
            xb[(size_t)row * 128 + c] = f2bf(v);
        }
    } else {
        int e = (blockIdx.x - ENC_BLOCKS) * 256 + t;
        if (e < ET) {
            int d = (e < E_EDGES) ? ei[E_EDGES + e] : (e - E_EDGES);
            atomicAdd(&deg[d], 1);
        }
    }
}

// ---------------------------------------------------------------------------
__global__ __launch_bounds__(1024) void scan_kernel(const int* __restrict__ deg,
                                                    int* __restrict__ off,
                                                    int* __restrict__ cursor) {
    __shared__ int sums[1024];
    int t = threadIdx.x;
    int base = t * 20;
    int tmp[20];
    int s = 0;
#pragma unroll
    for (int i = 0; i < 20; ++i) {
        int idx = base + i;
        int v = (idx < N_NODES) ? deg[idx] : 0;
        tmp[i] = s;
        s += v;
    }
    sums[t] = s;
    __syncthreads();
    for (int st = 1; st < 1024; st <<= 1) {
        int v = (t >= st) ? sums[t - st] : 0;
        __syncthreads();
        sums[t] += v;
        __syncthreads();
    }
    int bsum = (t == 0) ? 0 : sums[t - 1];
#pragma unroll
    for (int i = 0; i < 20; ++i) {
        int idx = base + i;
        if (idx < N_NODES) {
            int v = bsum + tmp[i];
            off[idx] = v;
            cursor[idx] = v;
        }
    }
    if (t == 1023) off[N_NODES] = sums[1023];
}

__global__ void scatter_kernel(const int* __restrict__ ei,
                               int* __restrict__ cursor, int* __restrict__ csr) {
    int e = blockIdx.x * 256 + threadIdx.x;
    if (e >= ET) return;
    int s, d;
    if (e < E_EDGES) { s = ei[e]; d = ei[E_EDGES + e]; }
    else             { s = d = e - E_EDGES; }
    int pos = atomicAdd(&cursor[d], 1);
    csr[pos] = s;
}

// ---------------------------------------------------------------------------
// dots for layer 0 (from bf16 xb0) + global-max of aS (keyed atomicMax).
__global__ __launch_bounds__(256) void dots_kernel(const ushort_t* __restrict__ xb,
                                                   const float* __restrict__ wtS,
                                                   const float* __restrict__ wtD,
                                                   float* __restrict__ aS,
                                                   float* __restrict__ aD,
                                                   uint_t* __restrict__ gmaxK) {
    __shared__ float ls[4][128], ld_[4][128];
    __shared__ uint_t bkey[4];
    int t = threadIdx.x;
    if (t < 4) bkey[t] = 0u;
    for (int i = t; i < 512; i += 256) {
        ls[i >> 7][i & 127] = wtS[i];
        ld_[i >> 7][i & 127] = wtD[i];
    }
    __syncthreads();
    int n = blockIdx.x * 32 + (t >> 3);
    int p = t & 7;
    const uint_t* xr = (const uint_t*)xb + (size_t)n * 64 + p * 8;
    float pS[4] = {0.f, 0.f, 0.f, 0.f}, pD[4] = {0.f, 0.f, 0.f, 0.f};
#pragma unroll
    for (int j = 0; j < 8; ++j) {
        uint_t u = xr[j];
        float f0 = bflo(u), f1 = bfhi(u);
        int d = p * 16 + j * 2;
#pragma unroll
        for (int h = 0; h < 4; ++h) {
            pS[h] = fmaf(f0, ls[h][d], fmaf(f1, ls[h][d + 1], pS[h]));
            pD[h] = fmaf(f0, ld_[h][d], fmaf(f1, ld_[h][d + 1], pD[h]));
        }
    }
#pragma unroll
    for (int st = 1; st < 8; st <<= 1) {
#pragma unroll
        for (int h = 0; h < 4; ++h) {
            pS[h] += __shfl_xor(pS[h], st);
            pD[h] += __shfl_xor(pD[h], st);
        }
    }
    if (p == 0) {
        *(float4*)(aS + (size_t)n * 4) = make_float4(pS[0], pS[1], pS[2], pS[3]);
        *(float4*)(aD + (size_t)n * 4) = make_float4(pD[0], pD[1], pD[2], pD[3]);
        atomicMax(&bkey[0], fkey(pS[0]));
        atomicMax(&bkey[1], fkey(pS[1]));
        atomicMax(&bkey[2], fkey(pS[2]));
        atomicMax(&bkey[3], fkey(pS[3]));
    }
    __syncthreads();
    if (t < 4) atomicMax(&gmaxK[t], bkey[t]);
}

// ---------------------------------------------------------------------------
// PHASE A: SINGLE-PASS half-wave-per-node softmax gather into U_lds.
// Global-max softmax: m_h = lr(gmax_h + aD_n) upper-bounds every edge logit,
// so no per-node max pass is needed (alpha invariant to the shift).
__device__ __forceinline__ void phaseA(int t, int n0,
                                       const uint2* __restrict__ xbv,
                                       const float* __restrict__ aS_cur,
                                       const float* __restrict__ aD_cur,
                                       const uint_t* __restrict__ gmaxK,
                                       const int* __restrict__ off,
                                       const int* __restrict__ csr,
                                       ushort_t (*U_lds)[512]) {
    int w = t >> 6, l = t & 63;
    int hw = l >> 5, q = l & 31;
    int row = w * 2 + hw;
    int n = n0 + row;
    int beg = off[n];
    int deg = off[n + 1] - beg;
    int base = hw << 5;

    float4 adv = *(const float4*)(aD_cur + (size_t)n * 4);
    float e;
    e = keyf(gmaxK[0]) + adv.x; float m0 = e > 0.f ? e : NEG_SLOPE * e;
    e = keyf(gmaxK[1]) + adv.y; float m1 = e > 0.f ? e : NEG_SLOPE * e;
    e = keyf(gmaxK[2]) + adv.z; float m2 = e > 0.f ? e : NEG_SLOPE * e;
    e = keyf(gmaxK[3]) + adv.w; float m3 = e > 0.f ? e : NEG_SLOPE * e;

    float a0[4] = {0.f, 0.f, 0.f, 0.f};
    float a1[4] = {0.f, 0.f, 0.f, 0.f};
    float a2[4] = {0.f, 0.f, 0.f, 0.f};
    float a3[4] = {0.f, 0.f, 0.f, 0.f};
    float4 zp = make_float4(0.f, 0.f, 0.f, 0.f);

    for (int c0 = 0; c0 < deg; c0 += 32) {
        int ce = min(32, deg - c0);
        int sl = 0;
        float4 wv = make_float4(0.f, 0.f, 0.f, 0.f);
        if (q < ce) {
            sl = csr[beg + c0 + q];
            float4 a = *(const float4*)(aS_cur + (size_t)sl * 4);
            e = a.x + adv.x; e = e > 0.f ? e : NEG_SLOPE * e; wv.x = __expf(e - m0);
            e = a.y + adv.y; e = e > 0.f ? e : NEG_SLOPE * e; wv.y = __expf(e - m1);
            e = a.z + adv.z; e = e > 0.f ? e : NEG_SLOPE * e; wv.z = __expf(e - m2);
            e = a.w + adv.w; e = e > 0.f ? e : NEG_SLOPE * e; wv.w = __expf(e - m3);
            zp.x += wv.x; zp.y += wv.y; zp.z += wv.z; zp.w += wv.w;
        }
#pragma unroll 8
        for (int j = 0; j < ce; ++j) {
            int src  = __shfl(sl, base + j);
            float w0 = __shfl(wv.x, base + j);
            float w1 = __shfl(wv.y, base + j);
            float w2 = __shfl(wv.z, base + j);
            float w3 = __shfl(wv.w, base + j);
            uint2 xv = xbv[(size_t)src * 32 + q];
            float f0 = bflo(xv.x), f1 = bfhi(xv.x), f2 = bflo(xv.y), f3 = bfhi(xv.y);
            a0[0] = fmaf(w0, f0, a0[0]); a0[1] = fmaf(w0, f1, a0[1]);
            a0[2] = fmaf(w0, f2, a0[2]); a0[3] = fmaf(w0, f3, a0[3]);
            a1[0] = fmaf(w1, f0, a1[0]); a1[1] = fmaf(w1, f1, a1[1]);
            a1[2] = fmaf(w1, f2, a1[2]); a1[3] = fmaf(w1, f3, a1[3]);
            a2[0] = fmaf(w2, f0, a2[0]); a2[1] = fmaf(w2, f1, a2[1]);
            a2[2] = fmaf(w2, f2, a2[2]); a2[3] = fmaf(w2, f3, a2[3]);
            a3[0] = fmaf(w3, f0, a3[0]); a3[1] = fmaf(w3, f1, a3[1]);
            a3[2] = fmaf(w3, f2, a3[2]); a3[3] = fmaf(w3, f3, a3[3]);
        }
    }

    // z reduce within half
#pragma unroll
    for (int st = 1; st < 32; st <<= 1) {
        zp.x += __shfl_xor(zp.x, st);
        zp.y += __shfl_xor(zp.y, st);
        zp.z += __shfl_xor(zp.z, st);
        zp.w += __shfl_xor(zp.w, st);
    }
    float iz0 = 1.f / zp.x, iz1 = 1.f / zp.y, iz2 = 1.f / zp.z, iz3 = 1.f / zp.w;

    uint_t* U32 = (uint_t*)&U_lds[row][0];
    int swz = (row & 7) << 2;
    int u0 = (2 * q) ^ swz, u1 = (2 * q + 1) ^ swz;
    U32[u0]        = pk2(a0[0] * iz0, a0[1] * iz0);
    U32[u1]        = pk2(a0[2] * iz0, a0[3] * iz0);
    U32[64 + u0]   = pk2(a1[0] * iz1, a1[1] * iz1);
    U32[64 + u1]   = pk2(a1[2] * iz1, a1[3] * iz1);
    U32[128 + u0]  = pk2(a2[0] * iz2, a2[1] * iz2);
    U32[128 + u1]  = pk2(a2[2] * iz2, a2[3] * iz2);
    U32[192 + u0]  = pk2(a3[0] * iz3, a3[1] * iz3);
    U32[192 + u1]  = pk2(a3[2] * iz3, a3[3] * iz3);
}

// ---------------------------------------------------------------------------
// PHASE B: 8-wave MFMA GEMM 16x512 @ 512x128 + residual + relu + fused dots
// (+ next-layer global-max). Dots scratch overlays U_lds after the k-loop.
__device__ __forceinline__ void phaseB(int t, int n0,
                                       ushort_t (*U_lds)[512],
                                       const ushort_t* __restrict__ Bp,
                                       const float* __restrict__ bias,
                                       const float* __restrict__ x_cur,
                                       float* __restrict__ x_next,
                                       ushort_t* __restrict__ xb_next,
                                       const float* __restrict__ wtS,
                                       const float* __restrict__ wtD,
                                       float* __restrict__ aS_next,
                                       float* __restrict__ aD_next,
                                       uint_t* __restrict__ gmaxK_next,
                                       int do_dots) {
    int w = t >> 6, l = t & 63;
    int r16 = l & 15, g = l >> 4;
    int bn0 = w * 16;
    const ushort_t* bcol = Bp + (size_t)(bn0 + r16) * 512 + g * 8;
    int arow_sw = (r16 & 7) << 3;

    f32x4 cacc = {};
#pragma unroll 4
    for (int k0 = 0; k0 < 512; k0 += 32) {
        bf16x8 a = *(const bf16x8*)&U_lds[r16][(k0 + g * 8) ^ arow_sw];
        bf16x8 bb = *(const bf16x8*)(bcol + k0);
        cacc = __builtin_amdgcn_mfma_f32_16x16x32_bf16(a, bb, cacc, 0, 0, 0);
    }

    int col = bn0 + r16;
    float bia = bias[col];
    float nx[4];
#pragma unroll
    for (int r = 0; r < 4; ++r) {
        int rl = g * 4 + r;
        int row = n0 + rl;
        float v = 0.25f * cacc[r] + bia;
        v = v > 0.f ? v : 0.f;
        float nv = x_cur[(size_t)row * 128 + col] + v;
        x_next[(size_t)row * 128 + col] = nv;
        xb_next[(size_t)row * 128 + col] = f2bf(nv);
        nx[r] = nv;
    }

    if (do_dots) {
        __syncthreads();
        float* ov = (float*)&U_lds[0][0];
        float wS[4], wD[4];
#pragma unroll
        for (int h = 0; h < 4; ++h) {
            wS[h] = wtS[h * 128 + col];
            wD[h] = wtD[h * 128 + col];
        }
#pragma unroll
        for (int r = 0; r < 4; ++r) {
            float sS[4], sD[4];
#pragma unroll
            for (int h = 0; h < 4; ++h) {
                sS[h] = nx[r] * wS[h];
                sD[h] = nx[r] * wD[h];
            }
#pragma unroll
            for (int st = 1; st < 16; st <<= 1)
#pragma unroll
                for (int h = 0; h < 4; ++h) {
                    sS[h] += __shfl_xor(sS[h], st);
                    sD[h] += __shfl_xor(sD[h], st);
                }
            if (r16 == 0) {
                int rl = g * 4 + r;
#pragma unroll
                for (int h = 0; h < 4; ++h) {
                    ov[(w * 16 + rl) * 4 + h] = sS[h];
                    ov[512 + (w * 16 + rl) * 4 + h] = sD[h];
                }
            }
        }
        __syncthreads();
        if (t < 64) {
            int rl = t >> 2, h = t & 3;
            int row = n0 + rl;
            float ssum = 0.f, dsum = 0.f;
#pragma unroll
            for (int ww = 0; ww < 8; ++ww) {
                ssum += ov[(ww * 16 + rl) * 4 + h];
                dsum += ov[512 + (ww * 16 + rl) * 4 + h];
            }
            aS_next[(size_t)row * 4 + h] = ssum;
            aD_next[(size_t)row * 4 + h] = dsum;
            // block-max of aS_next per head -> global keyed atomicMax
            float mv = ssum;
            mv = fmaxf(mv, __shfl_xor(mv, 4));
            mv = fmaxf(mv, __shfl_xor(mv, 8));
            mv = fmaxf(mv, __shfl_xor(mv, 16));
            mv = fmaxf(mv, __shfl_xor(mv, 32));
            if (t < 4) atomicMax(&gmaxK_next[t], fkey(mv));
        }
    }
}

// ---------------------------------------------------------------------------
__global__ __launch_bounds__(512) void gat_layer(const uint2* __restrict__ xbv,
                                                 const float* __restrict__ aS_cur,
                                                 const float* __restrict__ aD_cur,
                                                 const uint_t* __restrict__ gmaxK_cur,
                                                 const int* __restrict__ off,
                                                 const int* __restrict__ csr,
                                                 const ushort_t* __restrict__ Bp,
                                                 const float* __restrict__ bias,
                                                 const float* __restrict__ x_cur,
                                                 float* __restrict__ x_next,
                                                 ushort_t* __restrict__ xb_next,
                                                 const float* __restrict__ wtS,
                                                 const float* __restrict__ wtD,
                                                 float* __restrict__ aS_next,
                                                 float* __restrict__ aD_next,
                                                 uint_t* __restrict__ gmaxK_next,
                                                 int do_dots) {
    __shared__ ushort_t U_lds[LNODES][512];
    int t = threadIdx.x;
    int n0 = blockIdx.x * LNODES;
    phaseA(t, n0, xbv, aS_cur, aD_cur, gmaxK_cur, off, csr, U_lds);
    __syncthreads();
    phaseB(t, n0, U_lds, Bp, bias, x_cur, x_next, xb_next,
           wtS, wtD, aS_next, aD_next, gmaxK_next, do_dots);
}

// ---------------------------------------------------------------------------
// Prediction heads (MFMA attack head + strided vuln dot)
__global__ __launch_bounds__(256) void pred_kernel(const float* __restrict__ x,
                                                   const ushort_t* __restrict__ xb,
                                                   const ushort_t* __restrict__ W1p,
                                                   const float* __restrict__ b1,
                                                   const float* __restrict__ W2,
                                                   const float* __restrict__ b2,
                                                   const float* __restrict__ vW,
                                                   const float* __restrict__ vb,
                                                   float* __restrict__ out) {
    int t = threadIdx.x;
    int lane = t & 63, w = t >> 6;
    int wr = w >> 1, wc = w & 1;
    int bm0 = blockIdx.x * 64 + wr * 32;
    int bn0 = wc * 32;
    int r16 = lane & 15, g = lane >> 4;

    const ushort_t* arow = xb + (size_t)(bm0 + r16) * 128 + g * 8;
    const ushort_t* bcol = W1p + (size_t)(bn0 + r16) * 128 + g * 8;

    f32x4 acc[2][2] = {};
#pragma unroll
    for (int k0 = 0; k0 < 128; k0 += 32) {
        bf16x8 a0 = *(const bf16x8*)(arow + k0);
        bf16x8 a1 = *(const bf16x8*)(arow + 16 * 128 + k0);
        bf16x8 b0 = *(const bf16x8*)(bcol + k0);
        bf16x8 b1 = *(const bf16x8*)(bcol + 16 * 128 + k0);
        acc[0][0] = __builtin_amdgcn_mfma_f32_16x16x32_bf16(a0, b0, acc[0][0], 0, 0, 0);
        acc[0][1] = __builtin_amdgcn_mfma_f32_16x16x32_bf16(a0, b1, acc[0][1], 0, 0, 0);
        acc[1][0] = __builtin_amdgcn_mfma_f32_16x16x32_bf16(a1, b0, acc[1][0], 0, 0, 0);
        acc[1][1] = __builtin_amdgcn_mfma_f32_16x16x32_bf16(a1, b1, acc[1][1], 0, 0, 0);
    }

    __shared__ float pa[2][64];
    float b1c[2] = {b1[bn0 + r16], b1[bn0 + 16 + r16]};
    float w2c[2] = {W2[bn0 + r16], W2[bn0 + 16 + r16]};
#pragma unroll
    for (int fm = 0; fm < 2; ++fm)
#pragma unroll
        for (int r = 0; r < 4; ++r) {
            float h10 = acc[fm][0][r] + b1c[0]; h10 = h10 > 0.f ? h10 : 0.f;
            float h11 = acc[fm][1][r] + b1c[1]; h11 = h11 > 0.f ? h11 : 0.f;
            float s = h10 * w2c[0] + h11 * w2c[1];
#pragma unroll
            for (int st = 1; st < 16; st <<= 1) s += __shfl_xor(s, st);
            if (r16 == 0) pa[wc][wr * 32 + fm * 16 + g * 4 + r] = s;
        }
    __syncthreads();
    if (t < 64) {
        int row = blockIdx.x * 64 + t;
        if (row < N_NODES) {
            float pre = pa[0][t] + pa[1][t] + b2[0];
            out[row] = 1.f / (1.f + __expf(-pre));
        }
    }
    int vrow = blockIdx.x * 64 + w * 16 + (lane >> 2);
    int q = lane & 3;
    if (vrow < N_NODES) {
        const float* xr = x + (size_t)vrow * 128 + q * 32;
        float s = 0.f;
#pragma unroll
        for (int j = 0; j < 32; ++j) s = fmaf(xr[j], vW[q * 32 + j], s);
        s += __shfl_xor(s, 1);
        s += __shfl_xor(s, 2);
        if (q == 0)
            out[N_NODES + vrow] = 1.f / (1.f + __expf(-(s + vb[0])));
    }
}

// ---------------------------------------------------------------------------
extern "C" void kernel_launch(void* const* d_in, const int* in_sizes, int n_in,
                              void* d_out, int out_size, void* d_ws, size_t ws_size,
                              hipStream_t stream) {
    const float* nf    = (const float*)d_in[0];
    const int*   ei    = (const int*)d_in[1];
    const float* encW  = (const float*)d_in[2];
    const float* encb  = (const float*)d_in[3];
    const float* lin   = (const float*)d_in[4];
    const float* attS  = (const float*)d_in[5];
    const float* attD  = (const float*)d_in[6];
    const float* gbias = (const float*)d_in[7];
    const float* W1    = (const float*)d_in[8];
    const float* b1    = (const float*)d_in[9];
    const float* W2    = (const float*)d_in[10];
    const float* b2    = (const float*)d_in[11];
    const float* vW    = (const float*)d_in[12];
    const float* vb    = (const float*)d_in[13];
    float* out = (float*)d_out;

    char* ws = (char*)d_ws;
    size_t o = 0;
    auto alloc = [&](size_t bytes) {
        void* p = ws + o;
        o += (bytes + 255) & ~(size_t)255;
        return p;
    };
    float* x0     = (float*)alloc((size_t)N_PAD * 128 * 4);
    float* x1     = (float*)alloc((size_t)N_PAD * 128 * 4);
    ushort_t* xb0 = (ushort_t*)alloc((size_t)N_PAD * 128 * 2);
    ushort_t* xb1 = (ushort_t*)alloc((size_t)N_PAD * 128 * 2);
    ushort_t* Bp  = (ushort_t*)alloc((size_t)3 * 128 * 512 * 2);
    ushort_t* W1p = (ushort_t*)alloc((size_t)64 * 128 * 2);
    float* wtS    = (float*)alloc((size_t)3 * 512 * 4);
    float* wtD    = (float*)alloc((size_t)3 * 512 * 4);
    float* aS0    = (float*)alloc((size_t)N_NODES * 4 * 4);
    float* aD0    = (float*)alloc((size_t)N_NODES * 4 * 4);
    float* aS1    = (float*)alloc((size_t)N_NODES * 4 * 4);
    float* aD1    = (float*)alloc((size_t)N_NODES * 4 * 4);
    uint_t* gmaxK = (uint_t*)alloc(12 * 4);
    int* deg      = (int*)alloc((size_t)N_NODES * 4);
    int* cursor   = (int*)alloc((size_t)N_NODES * 4);
    int* offs     = (int*)alloc((size_t)(N_NODES + 1) * 4);
    int* csr      = (int*)alloc((size_t)ET * 4);

    const int HIST_BLOCKS = (ET + 255) / 256;

    pack_all<<<96, 256, 0, stream>>>(lin, attS, attD, W1, Bp, wtS, wtD, W1p, deg, gmaxK);
    enc_hist<<<ENC_BLOCKS + HIST_BLOCKS, 256, 0, stream>>>(nf, encW, encb, ei, x0, xb0, deg);
    scan_kernel<<<1, 1024, 0, stream>>>(deg, offs, cursor);
    scatter_kernel<<<HIST_BLOCKS, 256, 0, stream>>>(ei, cursor, csr);
    dots_kernel<<<N_NODES / 32, 256, 0, stream>>>(xb0, wtS, wtD, aS0, aD0, gmaxK);

    float*    xc[2]  = {x0, x1};
    ushort_t* xbc[2] = {xb0, xb1};
    float*    aSc[2] = {aS0, aS1};
    float*    aDc[2] = {aD0, aD1};
    for (int l = 0; l < 3; ++l) {
        int ci = l & 1, ni = ci ^ 1;
        int dd = (l < 2) ? 1 : 0;
        gat_layer<<<N_NODES / LNODES, 512, 0, stream>>>(
            (const uint2*)xbc[ci], aSc[ci], aDc[ci], gmaxK + l * 4, offs, csr,
            Bp + (size_t)l * 128 * 512, gbias + (size_t)l * 128,
            xc[ci], xc[ni], xbc[ni],
            wtS + (size_t)(l + 1 < 3 ? l + 1 : 0) * 512,
            wtD + (size_t)(l + 1 < 3 ? l + 1 : 0) * 512,
            aSc[ni], aDc[ni], gmaxK + (l + 1 < 3 ? l + 1 : 0) * 4, dd);
    }
    pred_kernel<<<N_PAD / 64, 256, 0, stream>>>(x1, xb1, W1p, b1, W2, b2, vW, vb, out);
}